// Round 10
// baseline (99.336 us; speedup 1.0000x reference)
//
#include <hip/hip_runtime.h>
#include <hip/hip_bf16.h>
#include <math.h>

#define B 4
#define T 128
#define S 512
#define H 512
// 2*log2(e): folds tanh's 2x and e->2 base change into the projection epilogue
#define QK_SCALE 2.8853900817779268f

// Hardware exp2 (v_exp_f32). Fallback = native exp path, never OCML-precise.
#if defined(__has_builtin)
#if __has_builtin(__builtin_amdgcn_exp2f)
#define EXP2F(x) __builtin_amdgcn_exp2f(x)
#else
#define EXP2F(x) __expf((x) * 0.6931471805599453f)
#endif
#else
#define EXP2F(x) __expf((x) * 0.6931471805599453f)
#endif

typedef __attribute__((ext_vector_type(8))) short bf16x8;
typedef __attribute__((ext_vector_type(4))) float f32x4;

__device__ __forceinline__ short f2b(float x) {   // f32 -> bf16 RNE
    unsigned int u = __float_as_uint(x);
    u += 0x7fffu + ((u >> 16) & 1u);
    return (short)(u >> 16);
}
__device__ __forceinline__ float fast_tanh(float x) {
    float e = __expf(2.0f * x);
    float r = __builtin_amdgcn_rcpf(e + 1.0f);
    return 1.0f - 2.0f * r;
}

// ---- phase 1: cvt inputs to bf16 (blocks 0..1151) + encT transpose (1152..2175) ----
// bf16 staging doubles as L2 prefetch/compaction for the latency-bound MFMA
// kernels (R8 lesson: inline f32 cvt in 1-wave/CU GEMMs = cold-HBM serial loads).
__global__ __launch_bounds__(256) void cvt_all(
    const float* __restrict__ q, const float* __restrict__ Ws,
    const float* __restrict__ Wh, const float* __restrict__ Wo,
    const float* __restrict__ enc, const int* __restrict__ slen,
    short* __restrict__ qb, short* __restrict__ wsb, short* __restrict__ whb,
    short* __restrict__ wob, short* __restrict__ eb, short* __restrict__ encT) {
    const int bid = blockIdx.x;
    const int tid = threadIdx.x;
    if (bid >= 1152) {   // encT[b][h][s] = bf16(enc[b][s][h])
        __shared__ short tb[32][33];
        const int bid2 = bid - 1152;
        const int b = bid2 >> 8, s0 = ((bid2 >> 4) & 15) * 32, h0 = (bid2 & 15) * 32;
        if (s0 >= slen[b]) return;   // masked cols: attn is exactly 0 there
        const int r = tid >> 3, c = (tid & 7) * 4;
        float4 a = *(const float4*)&enc[((size_t)(b * S + s0 + r)) * H + h0 + c];
        tb[c + 0][r] = f2b(a.x); tb[c + 1][r] = f2b(a.y);
        tb[c + 2][r] = f2b(a.z); tb[c + 3][r] = f2b(a.w);
        __syncthreads();
        ushort4 o = make_ushort4((unsigned short)tb[r][c], (unsigned short)tb[r][c + 1],
                                 (unsigned short)tb[r][c + 2], (unsigned short)tb[r][c + 3]);
        *(ushort4*)&encT[((size_t)(b * H + h0 + r)) * S + s0 + c] = o;
        return;
    }
    size_t i = ((size_t)bid * 256 + tid) * 8;
    const float* src; short* dst; size_t off;
    if (i < 262144)        { src = q;   dst = qb;  off = i; }
    else if (i < 524288)   { src = Ws;  dst = wsb; off = i - 262144; }
    else if (i < 786432)   { src = Wh;  dst = whb; off = i - 524288; }
    else if (i < 1310720)  { src = Wo;  dst = wob; off = i - 786432; }
    else                   { src = enc; dst = eb;  off = i - 1310720; }
    float4 a = *(const float4*)(src + off);
    float4 b = *(const float4*)(src + off + 4);
    ushort4 o0 = make_ushort4((unsigned short)f2b(a.x), (unsigned short)f2b(a.y),
                              (unsigned short)f2b(a.z), (unsigned short)f2b(a.w));
    ushort4 o1 = make_ushort4((unsigned short)f2b(b.x), (unsigned short)f2b(b.y),
                              (unsigned short)f2b(b.z), (unsigned short)f2b(b.w));
    *(ushort4*)(dst + off) = o0;
    *(ushort4*)(dst + off + 4) = o1;
}

// ---- MFMA wave-GEMM core: 32x32 per wave, direct global bf16 loads ----
#define MFMA4(APTR0, APTR1, BPTR0, BPTR1, KOFF)                                  \
    {                                                                            \
        bf16x8 a0 = *(const bf16x8*)((APTR0) + (KOFF));                          \
        bf16x8 a1 = *(const bf16x8*)((APTR1) + (KOFF));                          \
        bf16x8 b0 = *(const bf16x8*)((BPTR0) + (KOFF));                          \
        bf16x8 b1 = *(const bf16x8*)((BPTR1) + (KOFF));                          \
        acc00 = __builtin_amdgcn_mfma_f32_16x16x32_bf16(a0, b0, acc00, 0, 0, 0); \
        acc01 = __builtin_amdgcn_mfma_f32_16x16x32_bf16(a0, b1, acc01, 0, 0, 0); \
        acc10 = __builtin_amdgcn_mfma_f32_16x16x32_bf16(a1, b0, acc10, 0, 0, 0); \
        acc11 = __builtin_amdgcn_mfma_f32_16x16x32_bf16(a1, b1, acc11, 0, 0, 0); \
    }

// ---- phase 2: fused projections, Eq/Ek = exp2(GEMM * 2log2e)  (f32 out) ----
// exp factorization: exp2(q~+k~) = Eq*Ek -> score needs no exp.
__global__ __launch_bounds__(64) void mfma_proj(
    const short* __restrict__ qb, const short* __restrict__ eb,
    const short* __restrict__ wsb, const short* __restrict__ whb,
    const int* __restrict__ slen, float* __restrict__ qe, float* __restrict__ ke) {
    const int lane = threadIdx.x;
    const int r = lane & 15, kb = lane >> 4;
    const int n0 = blockIdx.x * 32;
    const int m0 = blockIdx.y * 32;
    const short* A; const short* W; float* C;
    if (m0 < 512) { A = qb + (size_t)m0 * H; W = wsb; C = qe + (size_t)m0 * H; }
    else {
        const int row = m0 - 512;
        if ((row & 511) >= slen[row >> 9]) return;   // fully-masked k-tile
        A = eb + (size_t)row * H; W = whb; C = ke + (size_t)row * H;
    }
    const short* a0p = A + (size_t)r * H + kb * 8;
    const short* a1p = a0p + 16 * H;
    const short* b0p = W + (size_t)(n0 + r) * H + kb * 8;
    const short* b1p = b0p + 16 * H;
    f32x4 acc00 = {0,0,0,0}, acc01 = {0,0,0,0}, acc10 = {0,0,0,0}, acc11 = {0,0,0,0};
#pragma unroll 4
    for (int k = 0; k < H; k += 32) MFMA4(a0p, a1p, b0p, b1p, k)
    const int cr = kb * 4, cc = r;
#pragma unroll
    for (int g = 0; g < 4; ++g) {
        C[(size_t)(cr + g) * H + n0 + cc]           = EXP2F(acc00[g] * QK_SCALE);
        C[(size_t)(cr + g) * H + n0 + 16 + cc]      = EXP2F(acc01[g] * QK_SCALE);
        C[(size_t)(16 + cr + g) * H + n0 + cc]      = EXP2F(acc10[g] * QK_SCALE);
        C[(size_t)(16 + cr + g) * H + n0 + 16 + cc] = EXP2F(acc11[g] * QK_SCALE);
    }
}

// ---- phase 3: partial score over one h-quarter (128 h), 8t x 16s per wave ----
// scoreh[qt][b*T+t][s] = -sum_h 2 v[h] * rcp(Eq[t,h]*Ek[s,h] + 1)
__global__ __launch_bounds__(64) void score_v4(
    const float* __restrict__ qe, const float* __restrict__ ke,
    const float* __restrict__ v, const int* __restrict__ slen,
    float* __restrict__ scoreh) {
    const int qt = blockIdx.z & 3;
    const int b = blockIdx.z >> 2;
    const int L = slen[b];
    const int sbase = blockIdx.x * 16;
    if (sbase >= L) return;
    const int tbase = blockIdx.y * 8;
    const int hbase = qt * 128;
    __shared__ __align__(16) float qs[8][132];
    __shared__ __align__(16) float ks[16][132];
    __shared__ __align__(16) float vsh[128];
    const int lane = threadIdx.x;
    {   // staging: q row r=lane>>3 (4 float4), k rows r and r+8 (8 float4)
        const int r = lane >> 3, c = (lane & 7) * 16;
        const float* qsrc = qe + (size_t)(b * T + tbase + r) * H + hbase + c;
        const float* k0src = ke + (size_t)(b * S + sbase + r) * H + hbase + c;
        const float* k1src = k0src + 8 * H;
#pragma unroll
        for (int j = 0; j < 4; ++j) {
            *(float4*)&qs[r][c + j * 4] = *(const float4*)(qsrc + j * 4);
            *(float4*)&ks[r][c + j * 4] = *(const float4*)(k0src + j * 4);
            *(float4*)&ks[8 + r][c + j * 4] = *(const float4*)(k1src + j * 4);
        }
        float2 vv = *(const float2*)&v[hbase + lane * 2];
        *(float2*)&vsh[lane * 2] = make_float2(-2.f * vv.x, -2.f * vv.y);
    }
    __syncthreads();
    const int t = lane >> 3, s0 = (lane & 7) * 2;
    const float* qrow = &qs[t][0];
    const float* k0r = &ks[s0][0];
    const float* k1r = &ks[s0 + 1][0];
    float a0 = 0.f, a1 = 0.f, c0 = 0.f, c1 = 0.f;
#pragma unroll 2
    for (int i = 0; i < 128; i += 4) {   // per elem: fma, rcp, fma
        float4 q4 = *(const float4*)&qrow[i];
        float4 ka = *(const float4*)&k0r[i];
        float4 kb = *(const float4*)&k1r[i];
        float4 v4 = *(const float4*)&vsh[i];
        a0 = fmaf(v4.x, __builtin_amdgcn_rcpf(fmaf(q4.x, ka.x, 1.f)), a0);
        c0 = fmaf(v4.x, __builtin_amdgcn_rcpf(fmaf(q4.x, kb.x, 1.f)), c0);
        a1 = fmaf(v4.y, __builtin_amdgcn_rcpf(fmaf(q4.y, ka.y, 1.f)), a1);
        c1 = fmaf(v4.y, __builtin_amdgcn_rcpf(fmaf(q4.y, kb.y, 1.f)), c1);
        a0 = fmaf(v4.z, __builtin_amdgcn_rcpf(fmaf(q4.z, ka.z, 1.f)), a0);
        c0 = fmaf(v4.z, __builtin_amdgcn_rcpf(fmaf(q4.z, kb.z, 1.f)), c0);
        a1 = fmaf(v4.w, __builtin_amdgcn_rcpf(fmaf(q4.w, ka.w, 1.f)), a1);
        c1 = fmaf(v4.w, __builtin_amdgcn_rcpf(fmaf(q4.w, kb.w, 1.f)), c1);
    }
    *(float2*)&scoreh[((size_t)qt * (B * T) + b * T + tbase + t) * S + sbase + s0] =
        make_float2(a0 + a1, c0 + c1);
}

// ---- phase 4 (fused tail): softmax -> ctx -> out-GEMM -> tanh -> LayerNorm ----
// One block per 16 t-rows of one b: 32 blocks x 1024 threads (16 waves).
// Everything row-local; attn and ctx live in LDS, never hit global.
__global__ __launch_bounds__(1024) void tail_kernel(
    const float* __restrict__ scoreh, const int* __restrict__ slen,
    const short* __restrict__ encT, const short* __restrict__ qb,
    const short* __restrict__ wob, const float* __restrict__ bias,
    const float* __restrict__ gamma, const float* __restrict__ beta,
    float* __restrict__ out) {
    __shared__ __align__(16) short attn_s[16][520];   // bf16 attn rows
    __shared__ __align__(16) short ctx_s[16][520];    // bf16 ctx rows
    __shared__ float red_s[16][16];
    __shared__ float red_q[16][16];
    __shared__ float fin[16][2];
    const int tid = threadIdx.x;
    const int w = tid >> 6, lane = tid & 63;
    const int b = blockIdx.x >> 3;
    const int tb = (blockIdx.x & 7) * 16;
    const int L = slen[b];

    {   // ---- A: softmax; wave w owns local row w; 8 cols/lane ----
        const int grow = b * T + tb + w;
        const size_t sl = (size_t)(B * T) * S;
        const float* p = scoreh + (size_t)grow * S + lane * 8;
        float x[8];
#pragma unroll
        for (int j = 0; j < 2; ++j) {
            float4 q0 = *(const float4*)(p + j * 4);
            float4 q1 = *(const float4*)(p + sl + j * 4);
            float4 q2 = *(const float4*)(p + 2 * sl + j * 4);
            float4 q3 = *(const float4*)(p + 3 * sl + j * 4);
            x[j * 4 + 0] = q0.x + q1.x + q2.x + q3.x;
            x[j * 4 + 1] = q0.y + q1.y + q2.y + q3.y;
            x[j * 4 + 2] = q0.z + q1.z + q2.z + q3.z;
            x[j * 4 + 3] = q0.w + q1.w + q2.w + q3.w;
        }
        const int cbase = lane * 8;
#pragma unroll
        for (int j = 0; j < 8; ++j)
            if (cbase + j >= L) x[j] = -INFINITY;
        float m = x[0];
#pragma unroll
        for (int j = 1; j < 8; ++j) m = fmaxf(m, x[j]);
#pragma unroll
        for (int off = 1; off < 64; off <<= 1) m = fmaxf(m, __shfl_xor(m, off));
        float e[8], sm = 0.f;
#pragma unroll
        for (int j = 0; j < 8; ++j) { e[j] = __expf(x[j] - m); sm += e[j]; }
#pragma unroll
        for (int off = 1; off < 64; off <<= 1) sm += __shfl_xor(sm, off);
        float inv = 1.0f / sm;   // masked cols -> exactly 0 in attn
        ushort4 u0 = make_ushort4((unsigned short)f2b(e[0] * inv), (unsigned short)f2b(e[1] * inv),
                                  (unsigned short)f2b(e[2] * inv), (unsigned short)f2b(e[3] * inv));
        ushort4 u1 = make_ushort4((unsigned short)f2b(e[4] * inv), (unsigned short)f2b(e[5] * inv),
                                  (unsigned short)f2b(e[6] * inv), (unsigned short)f2b(e[7] * inv));
        *(ushort4*)&attn_s[w][lane * 8]     = u0;
        *(ushort4*)&attn_s[w][lane * 8 + 4] = u1;
    }
    __syncthreads();

    const int r = lane & 15, kb = lane >> 4;
    const int n0 = w * 32;
    {   // ---- B: ctx[16][n0..n0+32] = attn @ encT^T; A from LDS ----
        // full K=512: masked attn entries are exact 0 -> 0 * (finite junk) = 0
        f32x4 cc0 = {0,0,0,0}, cc1 = {0,0,0,0};
        const short* bp0 = encT + ((size_t)(b * H + n0 + r)) * S + kb * 8;
        const short* bp1 = bp0 + (size_t)16 * S;
#pragma unroll 4
        for (int k = 0; k < S; k += 32) {
            bf16x8 a = *(const bf16x8*)&attn_s[r][k + kb * 8];
            cc0 = __builtin_amdgcn_mfma_f32_16x16x32_bf16(a, *(const bf16x8*)(bp0 + k), cc0, 0, 0, 0);
            cc1 = __builtin_amdgcn_mfma_f32_16x16x32_bf16(a, *(const bf16x8*)(bp1 + k), cc1, 0, 0, 0);
        }
        const int cr = kb * 4;
#pragma unroll
        for (int g = 0; g < 4; ++g) {
            ctx_s[cr + g][n0 + r]      = f2b(cc0[g]);
            ctx_s[cr + g][n0 + 16 + r] = f2b(cc1[g]);
        }
    }
    __syncthreads();

    // ---- C: pre[16][n0..n0+32] = tanh([ctx|query] @ Wo^T + bias) ----
    f32x4 o0 = {0,0,0,0}, o1 = {0,0,0,0};
    {
        const short* w0p = wob + ((size_t)(n0 + r)) * (2 * H) + kb * 8;
        const short* w1p = w0p + (size_t)16 * (2 * H);
#pragma unroll 4
        for (int k = 0; k < H; k += 32) {   // K 0..511: ctx from LDS
            bf16x8 a = *(const bf16x8*)&ctx_s[r][k + kb * 8];
            o0 = __builtin_amdgcn_mfma_f32_16x16x32_bf16(a, *(const bf16x8*)(w0p + k), o0, 0, 0, 0);
            o1 = __builtin_amdgcn_mfma_f32_16x16x32_bf16(a, *(const bf16x8*)(w1p + k), o1, 0, 0, 0);
        }
        const short* qp = qb + ((size_t)(b * T + tb + r)) * H + kb * 8;
#pragma unroll 4
        for (int k = 0; k < H; k += 32) {   // K 512..1023: query (bf16 staged)
            bf16x8 a = *(const bf16x8*)(qp + k);
            o0 = __builtin_amdgcn_mfma_f32_16x16x32_bf16(a, *(const bf16x8*)(w0p + H + k), o0, 0, 0, 0);
            o1 = __builtin_amdgcn_mfma_f32_16x16x32_bf16(a, *(const bf16x8*)(w1p + H + k), o1, 0, 0, 0);
        }
    }
    const int cr = kb * 4;
    float bn0 = bias[n0 + r], bn1 = bias[n0 + 16 + r];
    float v0[4], v1[4], sA[4], sQ[4];
#pragma unroll
    for (int g = 0; g < 4; ++g) {
        v0[g] = fast_tanh(o0[g] + bn0);
        v1[g] = fast_tanh(o1[g] + bn1);
        sA[g] = v0[g] + v1[g];
        sQ[g] = v0[g] * v0[g] + v1[g] * v1[g];
    }
    // ---- D: LayerNorm across 512 cols = 16 lanes x 16 waves ----
#pragma unroll
    for (int off = 1; off < 16; off <<= 1) {
#pragma unroll
        for (int g = 0; g < 4; ++g) {
            sA[g] += __shfl_xor(sA[g], off);
            sQ[g] += __shfl_xor(sQ[g], off);
        }
    }
    if (r == 0) {
#pragma unroll
        for (int g = 0; g < 4; ++g) {
            red_s[cr + g][w] = sA[g];
            red_q[cr + g][w] = sQ[g];
        }
    }
    __syncthreads();
    if (lane < 16) {   // wave w finalizes row w
        float ts = red_s[w][lane], tq = red_q[w][lane];
#pragma unroll
        for (int off = 1; off < 16; off <<= 1) {
            ts += __shfl_xor(ts, off);
            tq += __shfl_xor(tq, off);
        }
        if (lane == 0) {
            float mu = ts * (1.0f / H);
            float var = tq * (1.0f / H) - mu * mu;
            fin[w][0] = mu;
            fin[w][1] = rsqrtf(var + 1e-5f);
        }
    }
    __syncthreads();
#pragma unroll
    for (int g = 0; g < 4; ++g) {
        const int row = cr + g;
        const float mu = fin[row][0], inv = fin[row][1];
        const int col0 = n0 + r, col1 = n0 + 16 + r;
        const size_t orow = (size_t)(b * T + tb + row) * H;
        out[orow + col0] = (v0[g] - mu) * inv * gamma[col0] + beta[col0];
        out[orow + col1] = (v1[g] - mu) * inv * gamma[col1] + beta[col1];
    }
}

extern "C" void kernel_launch(void* const* d_in, const int* in_sizes, int n_in,
                              void* d_out, int out_size, void* d_ws, size_t ws_size,
                              hipStream_t stream) {
    const float* query = (const float*)d_in[0];
    const float* enc   = (const float*)d_in[1];
    const int*   slen  = (const int*)d_in[2];
    const float* W_h   = (const float*)d_in[3];
    const float* W_s   = (const float*)d_in[4];
    const float* v     = (const float*)d_in[5];
    const float* W_out = (const float*)d_in[6];
    const float* b_out = (const float*)d_in[7];
    const float* gamma = (const float*)d_in[8];
    const float* beta  = (const float*)d_in[9];
    float* out = (float*)d_out;

    // ---- workspace map, non-aliased (d_ws = 256 MB) ----
    char* base = (char*)d_ws;
    short* qb     = (short*)(base + 0);          // 512K  bf16 query
    short* wsb    = (short*)(base + 524288);     // 512K  bf16 W_s
    short* whb    = (short*)(base + 1048576);    // 512K  bf16 W_h
    short* wob    = (short*)(base + 1572864);    // 1M    bf16 W_out
    short* eb     = (short*)(base + 2621440);    // 2M    bf16 enc
    float* qe     = (float*)(base + 4718592);    // 1M    f32 exp2(q_proj~)
    float* ke     = (float*)(base + 5767168);    // 4M    f32 exp2(k_proj~)
    float* scoreh = (float*)(base + 9961472);    // 4M    f32 score quarters
    short* encT   = (short*)(base + 14155776);   // 2M    bf16 enc^T

    // cvt (1152 blocks) + encT transpose (1024 blocks, masked tiles skipped)
    cvt_all<<<dim3(2176), dim3(256), 0, stream>>>(query, W_s, W_h, W_out, enc, slen,
                                                  qb, wsb, whb, wob, eb, encT);
    mfma_proj<<<dim3(16, 80), dim3(64), 0, stream>>>(qb, eb, wsb, whb, slen, qe, ke);
    score_v4<<<dim3(32, 16, 16), dim3(64), 0, stream>>>(qe, ke, v, slen, scoreh);
    // fused tail: 32 blocks (B x 8 t-tiles) x 16 waves
    tail_kernel<<<dim3(32), dim3(1024), 0, stream>>>(scoreh, slen, encT, qb, wob,
                                                     b_out, gamma, beta, out);
}